// Round 4
// baseline (777.611 us; speedup 1.0000x reference)
//
#include <hip/hip_runtime.h>

#define N_PTS 1600
#define NSIDE 40
#define SNUM  512
#define BNUM  64
#define C1D   20
#define WID   128

typedef _Float16 h8  __attribute__((ext_vector_type(8)));
typedef _Float16 h2v __attribute__((ext_vector_type(2)));
typedef float    f4  __attribute__((ext_vector_type(4)));

__device__ __forceinline__ float silu_f(float x){ return x / (1.f + __expf(-x)); }
__device__ __forceinline__ void fma4(float4& a, float s, const float4 w){
    a.x += s*w.x; a.y += s*w.y; a.z += s*w.z; a.w += s*w.w;
}

// ---------------------------------------------------------------------------
// K0: blocks 0..49: pack data[64][1600] fp32 -> dataA f16 in MFMA A-fragment
//     layout: dataA[(chunk*4+mt)*64 + lane][8] where b=mt*16+(lane&15),
//     n=chunk*32+(lane>>4)*8+j.  (50 k-chunks of 32, 4 m-tiles of 16)
//     blocks 50..305: h2 = silu(v0e @ s_w1 + s_b1)  [512][128]
// ---------------------------------------------------------------------------
__global__ __launch_bounds__(256) void k0_prep(
    const float* __restrict__ data, const float* __restrict__ v0,
    const float* __restrict__ s_w1, const float* __restrict__ s_b1,
    _Float16* __restrict__ dataA, float* __restrict__ h2g)
{
    const int t = threadIdx.x;
    if (blockIdx.x < 50) {
        const int o  = blockIdx.x * 256 + t;       // 0..12799
        const int L  = o & 63, cm = o >> 6;        // cm 0..199
        const int mt = cm & 3, ch = cm >> 2;       // ch 0..49
        const int b  = mt * 16 + (L & 15);
        const int nb = ch * 32 + (L >> 4) * 8;
        const float* src = data + b * N_PTS + nb;
        h8 v;
        #pragma unroll
        for (int j = 0; j < 8; j++) v[j] = (_Float16)src[j];
        *(h8*)(dataA + (size_t)o * 8) = v;
    } else {
        const int g = (blockIdx.x - 50) * 256 + t;   // < 65536
        const int s = g >> 7, j = g & 127;
        float acc = s_b1[j];
        #pragma unroll
        for (int d = 0; d < 8; d++) {
            const float val = v0[s * 8 + d];
            float sv, cv;
            __sincosf(val, &sv, &cv);
            #pragma unroll
            for (int k = 0; k < 5; k++) {
                acc += sv * s_w1[(d*10 + k)     * WID + j];
                acc += cv * s_w1[(d*10 + 5 + k) * WID + j];
                const float ns = 2.f * sv * cv;
                const float nc = 1.f - 2.f * sv * sv;
                sv = ns; cv = nc;
            }
        }
        h2g[g] = silu_f(acc);
    }
}

// ---------------------------------------------------------------------------
// K1: one block per s. MFMA f16 throughout.
//   MLP: A=act[256pts][40pad f16] (K=32 padded, zeros persist in pad cols),
//        B=weights in registers (loaded once). Wave w owns points [64w,64w+64)
//        -> NO barriers in the main loop.
//   z:   Z[64b][20c] += dataA(global A-frags) x filtB(LDS B-frags), K=1600.
//   Output zg[s][c*64+b] = silu(sum/N), final (K2 consumes directly).
// ---------------------------------------------------------------------------
__global__ __launch_bounds__(256) void k1_filt_z(
    const _Float16* __restrict__ dataA, const float* __restrict__ v_last,
    const float* __restrict__ w1, const float* __restrict__ b1,
    const float* __restrict__ w2, const float* __restrict__ b2,
    const float* __restrict__ w3, const float* __restrict__ b3,
    float* __restrict__ zg)
{
    const int s    = blockIdx.x;
    const int t    = threadIdx.x;
    const int lane = t & 63;
    const int w    = t >> 6;
    const int q    = lane >> 4;
    const int l15  = lane & 15;

    __shared__ __align__(16) _Float16 wB[3][32][32];    //  6144 B [layer][cout][cin]
    __shared__ __align__(16) _Float16 act[256][40];     // 20480 B [point][cin pad40]
    __shared__ __align__(16) _Float16 filtB[32][264];   // 16896 B [cout][point pad264]
    __shared__ __align__(16) float    lbias[3][32];     //   384 B
    __shared__ __align__(16) float    red[4][64][21];   // 21504 B

    // ---- stage weights (zero-padded) ----
    const float* wsrc[3] = { w1, w2, w3 };
    for (int v = t; v < 3072; v += 256) {
        const int l = v >> 10, rem = v & 1023, c = rem >> 5, k = rem & 31;
        float x = 0.f;
        if (c < 20 && k < 20) x = wsrc[l][k * 20 + c];
        wB[l][c][k] = (_Float16)x;
    }
    if (t < 32)       lbias[0][t]    = (t < 20)      ? b1[t]    : 0.f;
    else if (t < 64)  lbias[1][t-32] = (t-32 < 20)   ? b2[t-32] : 0.f;
    else if (t < 96)  lbias[2][t-64] = (t-64 < 20)   ? b3[t-64] : 0.f;
    // zero act (pad cols persist as zero; real cols rewritten every tile)
    for (int v = t; v < 5120; v += 256) ((unsigned int*)act)[v] = 0u;
    __syncthreads();

    // ---- weight B-frags + biases into registers (resident whole kernel) ----
    h8 wf[3][2]; float bv[3][2];
    #pragma unroll
    for (int l = 0; l < 3; l++)
        #pragma unroll
        for (int nt = 0; nt < 2; nt++) {
            wf[l][nt] = *(const h8*)&wB[l][nt*16 + l15][q*8];
            bv[l][nt] = lbias[l][nt*16 + l15];
        }

    float Hm[9];
    #pragma unroll
    for (int k = 0; k < 9; k++) Hm[k] = (k == 0 || k == 4 || k == 8) ? 1.f : 0.f;
    #pragma unroll
    for (int k = 0; k < 8; k++) Hm[k] += 0.1f * v_last[s*8 + k];

    f4 zacc[4][2];
    #pragma unroll
    for (int mt = 0; mt < 4; mt++) { zacc[mt][0] = (f4)(0.f); zacc[mt][1] = (f4)(0.f); }
    const f4 zero4 = (f4)(0.f);

    for (int base = 0; base < N_PTS; base += 256) {
        const int tile_n = min(256, N_PTS - base);

        // ---- embedding (fp32) -> act rows, own point ----
        if (t < tile_n) {
            const int n = base + t;
            const int i = n / NSIDE;
            const int j = n - i * NSIDE;
            const float x = -1.f + (float)i * (2.f/39.f);
            const float y = -1.f + (float)j * (2.f/39.f);
            const float y0 = Hm[0]*x + Hm[1]*y + Hm[2];
            const float y1 = Hm[3]*x + Hm[4]*y + Hm[5];
            const float y2 = Hm[6]*x + Hm[7]*y + Hm[8];
            const float inv = 1.f / y2;
            const float tc0 = y0 * inv, tc1 = y1 * inv;
            float e[20];
            float sv0, cv0, sv1, cv1;
            __sincosf(tc0, &sv0, &cv0);
            __sincosf(tc1, &sv1, &cv1);
            #pragma unroll
            for (int k = 0; k < 5; k++) {
                e[k] = sv0; e[5+k] = cv0; e[10+k] = sv1; e[15+k] = cv1;
                const float ns0 = 2.f*sv0*cv0, nc0 = 1.f - 2.f*sv0*sv0;
                sv0 = ns0; cv0 = nc0;
                const float ns1 = 2.f*sv1*cv1, nc1 = 1.f - 2.f*sv1*sv1;
                sv1 = ns1; cv1 = nc1;
            }
            #pragma unroll
            for (int k = 0; k < 10; k++) {
                h2v hv; hv[0] = (_Float16)e[2*k]; hv[1] = (_Float16)e[2*k+1];
                *(h2v*)&act[t][2*k] = hv;
            }
        }

        // ---- MLP: wave-local M-tiles (points 16m..16m+16, m in [4w, 4w+cnt)) ----
        const int cnt = min(4, max(0, (tile_n >> 4) - 4*w));
        const int m0  = 4 * w;
        if (cnt > 0) {
            #pragma unroll
            for (int l = 0; l < 3; l++) {
                h8 af[4];
                for (int i = 0; i < cnt; i++)
                    af[i] = *(const h8*)&act[(m0+i)*16 + l15][q*8];
                f4 D[4][2];
                for (int i = 0; i < cnt; i++) {
                    D[i][0] = __builtin_amdgcn_mfma_f32_16x16x32_f16(af[i], wf[l][0], zero4, 0, 0, 0);
                    D[i][1] = __builtin_amdgcn_mfma_f32_16x16x32_f16(af[i], wf[l][1], zero4, 0, 0, 0);
                }
                for (int i = 0; i < cnt; i++) {
                    #pragma unroll
                    for (int nt = 0; nt < 2; nt++) {
                        const int c = nt*16 + l15;
                        if (c < 20) {
                            #pragma unroll
                            for (int r = 0; r < 4; r++) {
                                const int p = (m0+i)*16 + q*4 + r;
                                const float x = D[i][nt][r] + bv[l][nt];
                                if (l < 2) act[p][c]   = (_Float16)silu_f(x);
                                else       filtB[c][p] = (_Float16)x;
                            }
                        }
                    }
                }
            }
        }

        // ---- z-GEMM: wave w handles k-chunks 2w, 2w+1 of this tile ----
        for (int kc = 2*w; kc < 2*w + 2; kc++) {
            if (kc * 32 >= tile_n) break;
            const int gchunk = (base >> 5) + kc;
            const h8 bf0 = *(const h8*)&filtB[l15][kc*32 + q*8];
            const h8 bf1 = *(const h8*)&filtB[16 + l15][kc*32 + q*8];
            #pragma unroll
            for (int mt = 0; mt < 4; mt++) {
                const h8 afz = *(const h8*)(dataA + ((size_t)(gchunk*4 + mt)*64 + lane)*8);
                zacc[mt][0] = __builtin_amdgcn_mfma_f32_16x16x32_f16(afz, bf0, zacc[mt][0], 0, 0, 0);
                zacc[mt][1] = __builtin_amdgcn_mfma_f32_16x16x32_f16(afz, bf1, zacc[mt][1], 0, 0, 0);
            }
        }
    }

    // ---- cross-wave K-reduction of zacc, silu, store ----
    #pragma unroll
    for (int mt = 0; mt < 4; mt++) {
        #pragma unroll
        for (int r = 0; r < 4; r++) {
            const int b = mt*16 + q*4 + r;
            red[w][b][l15] = zacc[mt][0][r];
            if (l15 < 4) red[w][b][16 + l15] = zacc[mt][1][r];
        }
    }
    __syncthreads();
    for (int v = t; v < 1280; v += 256) {
        const int c = v >> 6, b = v & 63;
        const float sum = red[0][b][c] + red[1][b][c] + red[2][b][c] + red[3][b][c];
        zg[s*1280 + v] = silu_f(sum * (1.f / (float)N_PTS));
    }
}

// ---------------------------------------------------------------------------
// KA: filt2[s][c*128+w] = h2[s] @ s_w2 + s_b2.  M=512,K=128,N=2560.
// ---------------------------------------------------------------------------
__global__ __launch_bounds__(256) void ka_filt2(
    const float* __restrict__ h2g, const float* __restrict__ s_w2,
    const float* __restrict__ s_b2, float* __restrict__ f2g)
{
    const int s0  = blockIdx.x * 16;
    const int col = blockIdx.y * 256 + threadIdx.x;
    const int t   = threadIdx.x;
    __shared__ __align__(16) float h2t[128][16];
    for (int v = t; v < 2048; v += 256) {
        const int i = v & 127, ss = v >> 7;
        h2t[i][ss] = h2g[(s0 + ss) * WID + i];
    }
    __syncthreads();
    float4 acc[4];
    #pragma unroll
    for (int qq = 0; qq < 4; qq++) acc[qq] = make_float4(0.f, 0.f, 0.f, 0.f);
    #pragma unroll 4
    for (int i = 0; i < 128; i++) {
        const float wv = s_w2[i * 2560 + col];
        const float4* hh = (const float4*)&h2t[i][0];
        #pragma unroll
        for (int qq = 0; qq < 4; qq++) fma4(acc[qq], wv, hh[qq]);
    }
    const float bias = s_b2[col];
    const float* af = (const float*)acc;
    #pragma unroll
    for (int ss = 0; ss < 16; ss++)
        f2g[(s0 + ss) * 2560 + col] = af[ss] + bias;
}

// ---------------------------------------------------------------------------
// K2: grid 256 = (sgrp 128) x (whalf 2). Block: 4 s, 64 w.
// z is final (silu applied in K1). part[blk][b][w64]
// ---------------------------------------------------------------------------
__global__ __launch_bounds__(256) void k2_contract(
    const float* __restrict__ zg, const float* __restrict__ f2g,
    float* __restrict__ part)
{
    const int blk = blockIdx.x;
    const int sg  = blk >> 1;
    const int wh  = blk & 1;
    const int s0  = sg * 4;
    const int w0  = wh * 64;
    const int t   = threadIdx.x;
    __shared__ __align__(16) float zl[4*1280];   // [sp][c][b]
    __shared__ __align__(16) float fl[4*20*64];  // [sp][c][w64]
    #pragma unroll
    for (int sp = 0; sp < 4; sp++) {
        const int srow = (s0 + sp) * 1280;
        for (int r = t; r < 1280; r += 256)
            zl[sp*1280 + r] = zg[srow + r];
        for (int u = t; u < 1280; u += 256) {
            const int c = u >> 6, ww = u & 63;
            fl[sp*1280 + u] = f2g[(s0 + sp)*2560 + c*128 + w0 + ww];
        }
    }
    __syncthreads();
    const int ww = t & 63, bh = t >> 6;    // 4 b-groups of 16
    float4 acc[4];
    #pragma unroll
    for (int qq = 0; qq < 4; qq++) acc[qq] = make_float4(0.f, 0.f, 0.f, 0.f);
    #pragma unroll 4
    for (int sc = 0; sc < 80; sc++) {
        const float f = fl[sc * 64 + ww];
        const float4* zz = (const float4*)&zl[sc * 64 + bh * 16];
        #pragma unroll
        for (int qq = 0; qq < 4; qq++) fma4(acc[qq], f, zz[qq]);
    }
    const float* af = (const float*)acc;
    #pragma unroll
    for (int idx = 0; idx < 16; idx++) {
        const int b = bh * 16 + idx;
        part[blk * 4096 + b * 64 + ww] = af[idx];
    }
}

// ---------------------------------------------------------------------------
// K3: reduce partials over 128 s-groups, then FC tail.
// ---------------------------------------------------------------------------
__global__ __launch_bounds__(128) void k3_tail(
    const float* __restrict__ part,
    const float* __restrict__ fc1w, const float* __restrict__ fc1b,
    const float* __restrict__ fc2w, const float* __restrict__ fc2b,
    const float* __restrict__ pw,   const float* __restrict__ pb,
    float* __restrict__ out)
{
    const int b = blockIdx.x, t = threadIdx.x;
    const int wh = t >> 6, wl = t & 63;
    __shared__ float zb[128], r1[128], r2[128];
    float sum = 0.f;
    #pragma unroll 8
    for (int sg = 0; sg < 128; sg++)
        sum += part[((sg << 1) | wh) * 4096 + b * 64 + wl];
    zb[t] = sum * (1.f / (float)SNUM);
    __syncthreads();
    float a = fc1b[t];
    #pragma unroll 8
    for (int i = 0; i < 128; i++) a += zb[i] * fc1w[i * 128 + t];
    r1[t] = silu_f(a) + zb[t];
    __syncthreads();
    a = fc2b[t];
    #pragma unroll 8
    for (int i = 0; i < 128; i++) a += r1[i] * fc2w[i * 128 + t];
    r2[t] = silu_f(a) + r1[t];
    __syncthreads();
    if (t < 10) {
        float o = pb[t];
        #pragma unroll 8
        for (int i = 0; i < 128; i++) o += r2[i] * pw[i * 10 + t];
        out[b * 10 + t] = o;
    }
}

extern "C" void kernel_launch(void* const* d_in, const int* in_sizes, int n_in,
                              void* d_out, int out_size, void* d_ws, size_t ws_size,
                              hipStream_t stream) {
    const float* data   = (const float*)d_in[0];
    const float* v0     = (const float*)d_in[1];
    const float* v_last = (const float*)d_in[2];
    const float* fl_w1  = (const float*)d_in[3];
    const float* fl_b1  = (const float*)d_in[4];
    const float* fl_w2  = (const float*)d_in[5];
    const float* fl_b2  = (const float*)d_in[6];
    const float* fl_w3  = (const float*)d_in[7];
    const float* fl_b3  = (const float*)d_in[8];
    const float* s_w1   = (const float*)d_in[9];
    const float* s_b1   = (const float*)d_in[10];
    const float* s_w2   = (const float*)d_in[11];
    const float* s_b2   = (const float*)d_in[12];
    const float* fc1_w  = (const float*)d_in[13];
    const float* fc1_b  = (const float*)d_in[14];
    const float* fc2_w  = (const float*)d_in[15];
    const float* fc2_b  = (const float*)d_in[16];
    const float* pool_w = (const float*)d_in[17];
    const float* pool_b = (const float*)d_in[18];
    float* out = (float*)d_out;

    float* ws      = (float*)d_ws;
    _Float16* dataA = (_Float16*)ws;        // 102400 halves = 51200 float slots
    float* h2g   = ws    + 51200;           //  65536
    float* zg    = h2g   + 65536;           // 655360  [s][c][b] (final z)
    float* f2g   = zg    + 655360;          // 1310720 [s][c*128+w]
    float* part  = f2g   + 1310720;         // 1048576 [blk][b][w64]
    // total 3,131,392 floats = 12.5 MB

    k0_prep    <<<306, 256, 0, stream>>>(data, v0, s_w1, s_b1, dataA, h2g);
    k1_filt_z  <<<512, 256, 0, stream>>>(dataA, v_last, fl_w1, fl_b1, fl_w2, fl_b2,
                                         fl_w3, fl_b3, zg);
    ka_filt2   <<<dim3(32, 10), 256, 0, stream>>>(h2g, s_w2, s_b2, f2g);
    k2_contract<<<256, 256, 0, stream>>>(zg, f2g, part);
    k3_tail    <<<64, 128, 0, stream>>>(part, fc1_w, fc1_b, fc2_w, fc2_b,
                                        pool_w, pool_b, out);
}

// Round 6
// 216.916 us; speedup vs baseline: 3.5848x; 3.5848x over previous
//
#include <hip/hip_runtime.h>

#define N_PTS 1600
#define NSIDE 40
#define SNUM  512
#define BNUM  64
#define C1D   20
#define WID   128

typedef _Float16 h8  __attribute__((ext_vector_type(8)));
typedef __fp16   h2v __attribute__((ext_vector_type(2)));   // type for cvt_pkrtz/fdot2
typedef float    f4  __attribute__((ext_vector_type(4)));

__device__ __forceinline__ float silu_f(float x){ return x / (1.f + __expf(-x)); }
__device__ __forceinline__ void fma4(float4& a, float s, const float4 w){
    a.x += s*w.x; a.y += s*w.y; a.z += s*w.z; a.w += s*w.w;
}

// ---------------------------------------------------------------------------
// K0: blocks 0..49: pack data[64][1600] fp32 -> dataA f16 in MFMA A-fragment
//     layout (verified round 4): dataA[(chunk*4+mt)*64 + lane][8],
//     b = mt*16+(lane&15), n = chunk*32+(lane>>4)*8+j.
//     blocks 50..305: h2 = silu(v0e @ s_w1 + s_b1)  [512][128]
// ---------------------------------------------------------------------------
__global__ __launch_bounds__(256) void k0_prep(
    const float* __restrict__ data, const float* __restrict__ v0,
    const float* __restrict__ s_w1, const float* __restrict__ s_b1,
    _Float16* __restrict__ dataA, float* __restrict__ h2g)
{
    const int t = threadIdx.x;
    if (blockIdx.x < 50) {
        const int o  = blockIdx.x * 256 + t;       // 0..12799
        const int L  = o & 63, cm = o >> 6;        // cm 0..199
        const int mt = cm & 3, ch = cm >> 2;       // ch 0..49
        const int b  = mt * 16 + (L & 15);
        const int nb = ch * 32 + (L >> 4) * 8;
        const float* src = data + b * N_PTS + nb;
        h8 v;
        #pragma unroll
        for (int j = 0; j < 8; j++) v[j] = (_Float16)src[j];
        *(h8*)(dataA + (size_t)o * 8) = v;
    } else {
        const int g = (blockIdx.x - 50) * 256 + t;   // < 65536
        const int s = g >> 7, j = g & 127;
        float acc = s_b1[j];
        #pragma unroll
        for (int d = 0; d < 8; d++) {
            const float val = v0[s * 8 + d];
            float sv, cv;
            __sincosf(val, &sv, &cv);
            #pragma unroll
            for (int k = 0; k < 5; k++) {
                acc += sv * s_w1[(d*10 + k)     * WID + j];
                acc += cv * s_w1[(d*10 + 5 + k) * WID + j];
                const float ns = 2.f * sv * cv;
                const float nc = 1.f - 2.f * sv * sv;
                sv = ns; cv = nc;
            }
        }
        h2g[g] = silu_f(acc);
    }
}

// ---------------------------------------------------------------------------
// K1 helpers
// ---------------------------------------------------------------------------
__device__ __forceinline__ void embed_pt(int n, const float Hm[9], h2v e2[10])
{
    const int i = n / NSIDE;
    const int j = n - i * NSIDE;
    const float x = -1.f + (float)i * (2.f/39.f);
    const float y = -1.f + (float)j * (2.f/39.f);
    const float y0 = Hm[0]*x + Hm[1]*y + Hm[2];
    const float y1 = Hm[3]*x + Hm[4]*y + Hm[5];
    const float y2 = Hm[6]*x + Hm[7]*y + Hm[8];
    const float inv = 1.f / y2;
    const float t0 = y0 * inv, t1 = y1 * inv;
    float e[20];
    float sv0, cv0, sv1, cv1;
    __sincosf(t0, &sv0, &cv0);
    __sincosf(t1, &sv1, &cv1);
    #pragma unroll
    for (int k = 0; k < 5; k++) {
        e[k] = sv0; e[5+k] = cv0; e[10+k] = sv1; e[15+k] = cv1;
        const float ns0 = 2.f*sv0*cv0, nc0 = 1.f - 2.f*sv0*sv0; sv0 = ns0; cv0 = nc0;
        const float ns1 = 2.f*sv1*cv1, nc1 = 1.f - 2.f*sv1*sv1; sv1 = ns1; cv1 = nc1;
    }
    #pragma unroll
    for (int k = 0; k < 10; k++)
        e2[k] = __builtin_amdgcn_cvt_pkrtz(e[2*k], e[2*k+1]);
}

// one 20->20 layer for two points; weights read ONCE (b128 broadcast), fdot2
__device__ __forceinline__ void layer20(const h2v e2a[10], const h2v e2b[10],
    const h2v (*wL)[20], const float* bL, float hA[20], float hB[20])
{
    #pragma unroll
    for (int qq = 0; qq < 5; qq++) {
        const f4 bvv = ((const f4*)bL)[qq];
        hA[4*qq+0] = bvv[0]; hA[4*qq+1] = bvv[1]; hA[4*qq+2] = bvv[2]; hA[4*qq+3] = bvv[3];
        hB[4*qq+0] = bvv[0]; hB[4*qq+1] = bvv[1]; hB[4*qq+2] = bvv[2]; hB[4*qq+3] = bvv[3];
    }
    #pragma unroll
    for (int k = 0; k < 10; k++) {
        const uint4* Wp = (const uint4*)&wL[k][0];
        const h2v ea = e2a[k], eb = e2b[k];
        #pragma unroll
        for (int qq = 0; qq < 5; qq++) {
            const uint4 Wv = Wp[qq];
            const h2v w0 = __builtin_bit_cast(h2v, Wv.x);
            const h2v w1 = __builtin_bit_cast(h2v, Wv.y);
            const h2v w2 = __builtin_bit_cast(h2v, Wv.z);
            const h2v w3 = __builtin_bit_cast(h2v, Wv.w);
            hA[4*qq+0] = __builtin_amdgcn_fdot2(ea, w0, hA[4*qq+0], false);
            hA[4*qq+1] = __builtin_amdgcn_fdot2(ea, w1, hA[4*qq+1], false);
            hA[4*qq+2] = __builtin_amdgcn_fdot2(ea, w2, hA[4*qq+2], false);
            hA[4*qq+3] = __builtin_amdgcn_fdot2(ea, w3, hA[4*qq+3], false);
            hB[4*qq+0] = __builtin_amdgcn_fdot2(eb, w0, hB[4*qq+0], false);
            hB[4*qq+1] = __builtin_amdgcn_fdot2(eb, w1, hB[4*qq+1], false);
            hB[4*qq+2] = __builtin_amdgcn_fdot2(eb, w2, hB[4*qq+2], false);
            hB[4*qq+3] = __builtin_amdgcn_fdot2(eb, w3, hB[4*qq+3], false);
        }
    }
}

// ---------------------------------------------------------------------------
// K1: one block per s. MLP on VALU (f16x2 dot2, P=2 points/thread),
// filt -> LDS B-layout [c][p] (f16), z-GEMM via MFMA with global A-frags.
// Tiles of 512 points (3x512 + 64 tail). zg[s][c*64+b] final (silu applied).
// ---------------------------------------------------------------------------
__global__ __launch_bounds__(256) void k1_filt_z(
    const _Float16* __restrict__ dataA, const float* __restrict__ v_last,
    const float* __restrict__ w1, const float* __restrict__ b1,
    const float* __restrict__ w2, const float* __restrict__ b2,
    const float* __restrict__ w3, const float* __restrict__ b3,
    float* __restrict__ zg)
{
    const int s    = blockIdx.x;
    const int t    = threadIdx.x;
    const int lane = t & 63;
    const int w    = t >> 6;
    const int q    = lane >> 4;
    const int l15  = lane & 15;

    __shared__ __align__(16) h2v   wW[3][10][20];     // 2400 B packed (cin-pair, cout)
    __shared__ __align__(16) float lbias[3][20];      //  240 B
    __shared__ __align__(16) unsigned char pool[21504];
    _Float16* filtB = (_Float16*)pool;                // [20][520] = 20800 B
    float*    red   = (float*)pool;                   // [4][64][21] = 21504 B (after last MFMA)

    const float* wsrc[3] = { w1, w2, w3 };
    const float* bsrc[3] = { b1, b2, b3 };
    for (int v = t; v < 600; v += 256) {
        const int l = v / 200, rem = v - l*200;
        const int k = rem / 20, c = rem - k*20;
        wW[l][k][c] = __builtin_amdgcn_cvt_pkrtz(wsrc[l][(2*k)*20 + c],
                                                 wsrc[l][(2*k+1)*20 + c]);
    }
    if (t < 60) lbias[t/20][t%20] = bsrc[t/20][t%20];

    float Hm[9];
    #pragma unroll
    for (int k = 0; k < 9; k++) Hm[k] = (k == 0 || k == 4 || k == 8) ? 1.f : 0.f;
    #pragma unroll
    for (int k = 0; k < 8; k++) Hm[k] += 0.1f * v_last[s*8 + k];

    f4 zacc[4][2];
    #pragma unroll
    for (int mt = 0; mt < 4; mt++) { zacc[mt][0] = (f4)(0.f); zacc[mt][1] = (f4)(0.f); }

    __syncthreads();

    for (int base = 0; base < N_PTS; base += 512) {
        const int tn = min(512, N_PTS - base);     // 512,512,512,64
        if (t < tn) {
            const bool a1 = (t + 256) < tn;
            const int n0 = base + t;
            const int n1 = a1 ? (n0 + 256) : n0;
            h2v e2a[10], e2b[10];
            embed_pt(n0, Hm, e2a);
            embed_pt(n1, Hm, e2b);
            float hA[20], hB[20];
            // layer 1
            layer20(e2a, e2b, wW[0], lbias[0], hA, hB);
            #pragma unroll
            for (int k = 0; k < 10; k++) {
                e2a[k] = __builtin_amdgcn_cvt_pkrtz(silu_f(hA[2*k]), silu_f(hA[2*k+1]));
                e2b[k] = __builtin_amdgcn_cvt_pkrtz(silu_f(hB[2*k]), silu_f(hB[2*k+1]));
            }
            // layer 2
            layer20(e2a, e2b, wW[1], lbias[1], hA, hB);
            #pragma unroll
            for (int k = 0; k < 10; k++) {
                e2a[k] = __builtin_amdgcn_cvt_pkrtz(silu_f(hA[2*k]), silu_f(hA[2*k+1]));
                e2b[k] = __builtin_amdgcn_cvt_pkrtz(silu_f(hB[2*k]), silu_f(hB[2*k+1]));
            }
            // layer 3 -> filt (f16, B-layout [c][p]; writes contiguous across lanes)
            layer20(e2a, e2b, wW[2], lbias[2], hA, hB);
            #pragma unroll
            for (int c = 0; c < 20; c++) {
                filtB[c*520 + t] = (_Float16)hA[c];
                if (a1) filtB[c*520 + 256 + t] = (_Float16)hB[c];
            }
        }
        __syncthreads();

        // z-GEMM: Z[64b][20c] += dataA-chunks x filtB, waves stride k-chunks
        const int nkc = tn >> 5;
        const int r1row = (l15 < 4) ? (16 + l15) : 0;   // clamped; extra cols ignored
        for (int kc = w; kc < nkc; kc += 4) {
            const int gchunk = (base >> 5) + kc;
            const h8 bf0 = *(const h8*)&filtB[(size_t)l15  * 520 + kc*32 + q*8];
            const h8 bf1 = *(const h8*)&filtB[(size_t)r1row* 520 + kc*32 + q*8];
            #pragma unroll
            for (int mt = 0; mt < 4; mt++) {
                const h8 afz = *(const h8*)(dataA + ((size_t)(gchunk*4 + mt)*64 + lane)*8);
                zacc[mt][0] = __builtin_amdgcn_mfma_f32_16x16x32_f16(afz, bf0, zacc[mt][0], 0, 0, 0);
                zacc[mt][1] = __builtin_amdgcn_mfma_f32_16x16x32_f16(afz, bf1, zacc[mt][1], 0, 0, 0);
            }
        }
        __syncthreads();
    }

    // cross-wave K-reduction (red overlays filtB; safe after trailing barrier)
    #pragma unroll
    for (int mt = 0; mt < 4; mt++) {
        #pragma unroll
        for (int r = 0; r < 4; r++) {
            const int b = mt*16 + q*4 + r;
            red[(w*64 + b)*21 + l15] = zacc[mt][0][r];
            if (l15 < 4) red[(w*64 + b)*21 + 16 + l15] = zacc[mt][1][r];
        }
    }
    __syncthreads();
    for (int v = t; v < 1280; v += 256) {
        const int c = v >> 6, b = v & 63;
        const float sum = red[b*21 + c] + red[(64+b)*21 + c]
                        + red[(128+b)*21 + c] + red[(192+b)*21 + c];
        zg[s*1280 + v] = silu_f(sum * (1.f / (float)N_PTS));
    }
}

// ---------------------------------------------------------------------------
// KA: filt2[s][c*128+w] = h2[s] @ s_w2 + s_b2.  M=512,K=128,N=2560.
// ---------------------------------------------------------------------------
__global__ __launch_bounds__(256) void ka_filt2(
    const float* __restrict__ h2g, const float* __restrict__ s_w2,
    const float* __restrict__ s_b2, float* __restrict__ f2g)
{
    const int s0  = blockIdx.x * 16;
    const int col = blockIdx.y * 256 + threadIdx.x;
    const int t   = threadIdx.x;
    __shared__ __align__(16) float h2t[128][16];
    for (int v = t; v < 2048; v += 256) {
        const int i = v & 127, ss = v >> 7;
        h2t[i][ss] = h2g[(s0 + ss) * WID + i];
    }
    __syncthreads();
    float4 acc[4];
    #pragma unroll
    for (int qq = 0; qq < 4; qq++) acc[qq] = make_float4(0.f, 0.f, 0.f, 0.f);
    #pragma unroll 4
    for (int i = 0; i < 128; i++) {
        const float wv = s_w2[i * 2560 + col];
        const float4* hh = (const float4*)&h2t[i][0];
        #pragma unroll
        for (int qq = 0; qq < 4; qq++) fma4(acc[qq], wv, hh[qq]);
    }
    const float bias = s_b2[col];
    const float* af = (const float*)acc;
    #pragma unroll
    for (int ss = 0; ss < 16; ss++)
        f2g[(s0 + ss) * 2560 + col] = af[ss] + bias;
}

// ---------------------------------------------------------------------------
// K2: grid 256 = (sgrp 128) x (whalf 2). Block: 4 s, 64 w. part[blk][b][w64]
// ---------------------------------------------------------------------------
__global__ __launch_bounds__(256) void k2_contract(
    const float* __restrict__ zg, const float* __restrict__ f2g,
    float* __restrict__ part)
{
    const int blk = blockIdx.x;
    const int sg  = blk >> 1;
    const int wh  = blk & 1;
    const int s0  = sg * 4;
    const int w0  = wh * 64;
    const int t   = threadIdx.x;
    __shared__ __align__(16) float zl[4*1280];   // [sp][c][b]
    __shared__ __align__(16) float fl[4*20*64];  // [sp][c][w64]
    #pragma unroll
    for (int sp = 0; sp < 4; sp++) {
        const int srow = (s0 + sp) * 1280;
        for (int r = t; r < 1280; r += 256)
            zl[sp*1280 + r] = zg[srow + r];
        for (int u = t; u < 1280; u += 256) {
            const int c = u >> 6, ww = u & 63;
            fl[sp*1280 + u] = f2g[(s0 + sp)*2560 + c*128 + w0 + ww];
        }
    }
    __syncthreads();
    const int ww = t & 63, bh = t >> 6;
    float4 acc[4];
    #pragma unroll
    for (int qq = 0; qq < 4; qq++) acc[qq] = make_float4(0.f, 0.f, 0.f, 0.f);
    #pragma unroll 4
    for (int sc = 0; sc < 80; sc++) {
        const float f = fl[sc * 64 + ww];
        const float4* zz = (const float4*)&zl[sc * 64 + bh * 16];
        #pragma unroll
        for (int qq = 0; qq < 4; qq++) fma4(acc[qq], f, zz[qq]);
    }
    const float* af = (const float*)acc;
    #pragma unroll
    for (int idx = 0; idx < 16; idx++) {
        const int b = bh * 16 + idx;
        part[blk * 4096 + b * 64 + ww] = af[idx];
    }
}

// ---------------------------------------------------------------------------
// K3: reduce partials over 128 s-groups, then FC tail.
// ---------------------------------------------------------------------------
__global__ __launch_bounds__(128) void k3_tail(
    const float* __restrict__ part,
    const float* __restrict__ fc1w, const float* __restrict__ fc1b,
    const float* __restrict__ fc2w, const float* __restrict__ fc2b,
    const float* __restrict__ pw,   const float* __restrict__ pb,
    float* __restrict__ out)
{
    const int b = blockIdx.x, t = threadIdx.x;
    const int wh = t >> 6, wl = t & 63;
    __shared__ float zb[128], r1[128], r2[128];
    float sum = 0.f;
    #pragma unroll 8
    for (int sg = 0; sg < 128; sg++)
        sum += part[((sg << 1) | wh) * 4096 + b * 64 + wl];
    zb[t] = sum * (1.f / (float)SNUM);
    __syncthreads();
    float a = fc1b[t];
    #pragma unroll 8
    for (int i = 0; i < 128; i++) a += zb[i] * fc1w[i * 128 + t];
    r1[t] = silu_f(a) + zb[t];
    __syncthreads();
    a = fc2b[t];
    #pragma unroll 8
    for (int i = 0; i < 128; i++) a += r1[i] * fc2w[i * 128 + t];
    r2[t] = silu_f(a) + r1[t];
    __syncthreads();
    if (t < 10) {
        float o = pb[t];
        #pragma unroll 8
        for (int i = 0; i < 128; i++) o += r2[i] * pw[i * 10 + t];
        out[b * 10 + t] = o;
    }
}

extern "C" void kernel_launch(void* const* d_in, const int* in_sizes, int n_in,
                              void* d_out, int out_size, void* d_ws, size_t ws_size,
                              hipStream_t stream) {
    const float* data   = (const float*)d_in[0];
    const float* v0     = (const float*)d_in[1];
    const float* v_last = (const float*)d_in[2];
    const float* fl_w1  = (const float*)d_in[3];
    const float* fl_b1  = (const float*)d_in[4];
    const float* fl_w2  = (const float*)d_in[5];
    const float* fl_b2  = (const float*)d_in[6];
    const float* fl_w3  = (const float*)d_in[7];
    const float* fl_b3  = (const float*)d_in[8];
    const float* s_w1   = (const float*)d_in[9];
    const float* s_b1   = (const float*)d_in[10];
    const float* s_w2   = (const float*)d_in[11];
    const float* s_b2   = (const float*)d_in[12];
    const float* fc1_w  = (const float*)d_in[13];
    const float* fc1_b  = (const float*)d_in[14];
    const float* fc2_w  = (const float*)d_in[15];
    const float* fc2_b  = (const float*)d_in[16];
    const float* pool_w = (const float*)d_in[17];
    const float* pool_b = (const float*)d_in[18];
    float* out = (float*)d_out;

    float* ws      = (float*)d_ws;
    _Float16* dataA = (_Float16*)ws;        // 102400 halves = 51200 float slots
    float* h2g   = ws    + 51200;           //  65536
    float* zg    = h2g   + 65536;           // 655360  [s][c][b] (final z)
    float* f2g   = zg    + 655360;          // 1310720 [s][c*128+w]
    float* part  = f2g   + 1310720;         // 1048576 [blk][b][w64]

    k0_prep    <<<306, 256, 0, stream>>>(data, v0, s_w1, s_b1, dataA, h2g);
    k1_filt_z  <<<512, 256, 0, stream>>>(dataA, v_last, fl_w1, fl_b1, fl_w2, fl_b2,
                                         fl_w3, fl_b3, zg);
    ka_filt2   <<<dim3(32, 10), 256, 0, stream>>>(h2g, s_w2, s_b2, f2g);
    k2_contract<<<256, 256, 0, stream>>>(zg, f2g, part);
    k3_tail    <<<64, 128, 0, stream>>>(part, fc1_w, fc1_b, fc2_w, fc2_b,
                                        pool_w, pool_b, out);
}